// Round 7
// baseline (3913.149 us; speedup 1.0000x reference)
//
#include <hip/hip_runtime.h>
#include <stdint.h>

#define B_ 64
#define T_ 2048
#define I_ 256
#define H_ 256
#define G3 768

typedef _Float16 half2v __attribute__((ext_vector_type(2)));
typedef _Float16 half8v __attribute__((ext_vector_type(8)));

#if __has_builtin(__builtin_amdgcn_fdot2)
#define FDOT2(a, b, c) __builtin_amdgcn_fdot2((a), (b), (c), false)
#else
#define FDOT2(a, b, c) fmaf((float)(a)[1], (float)(b)[1], fmaf((float)(a)[0], (float)(b)[0], (c)))
#endif

// ---------------- Phase 1 ---------------- (unchanged; ~0.75 ms)
__global__ __launch_bounds__(256) void gi_gemm(
    const float* __restrict__ x, const float* __restrict__ Wih,
    const float* __restrict__ bih, const float* __restrict__ bhh,
    float* __restrict__ gi, int t0)
{
  const int t  = t0 + blockIdx.x;
  const int n0 = blockIdx.y * 64;
  __shared__ float As[32][68];
  __shared__ float Bs[32][68];
  const int tid = threadIdx.x;
  const int ty = tid >> 4, tx = tid & 15;
  const int lr = tid >> 3;
  const int lk = (tid & 7) << 2;
  float acc[4][4] = {};

  for (int kc = 0; kc < I_; kc += 32) {
    float4 a0 = *(const float4*)(x + ((size_t)lr        * T_ + t) * I_ + kc + lk);
    float4 a1 = *(const float4*)(x + ((size_t)(lr + 32) * T_ + t) * I_ + kc + lk);
    float4 b0 = *(const float4*)(Wih + (size_t)(n0 + lr)      * I_ + kc + lk);
    float4 b1 = *(const float4*)(Wih + (size_t)(n0 + lr + 32) * I_ + kc + lk);
    __syncthreads();
    As[lk+0][lr]    = a0.x; As[lk+1][lr]    = a0.y; As[lk+2][lr]    = a0.z; As[lk+3][lr]    = a0.w;
    As[lk+0][lr+32] = a1.x; As[lk+1][lr+32] = a1.y; As[lk+2][lr+32] = a1.z; As[lk+3][lr+32] = a1.w;
    Bs[lk+0][lr]    = b0.x; Bs[lk+1][lr]    = b0.y; Bs[lk+2][lr]    = b0.z; Bs[lk+3][lr]    = b0.w;
    Bs[lk+0][lr+32] = b1.x; Bs[lk+1][lr+32] = b1.y; Bs[lk+2][lr+32] = b1.z; Bs[lk+3][lr+32] = b1.w;
    __syncthreads();
    #pragma unroll
    for (int kk = 0; kk < 32; ++kk) {
      float4 av = *(const float4*)(&As[kk][ty << 2]);
      float4 bv = *(const float4*)(&Bs[kk][tx << 2]);
      float av_[4] = {av.x, av.y, av.z, av.w};
      float bv_[4] = {bv.x, bv.y, bv.z, bv.w};
      #pragma unroll
      for (int i = 0; i < 4; ++i)
        #pragma unroll
        for (int u = 0; u < 4; ++u)
          acc[i][u] = fmaf(av_[i], bv_[u], acc[i][u]);
    }
  }

  const int colb = n0 + (tx << 2);
  float4 bi = *(const float4*)(bih + colb);
  float4 bh = *(const float4*)(bhh + colb);
  float4 badd;
  badd.x = bi.x + (colb + 0 < 512 ? bh.x : 0.f);
  badd.y = bi.y + (colb + 1 < 512 ? bh.y : 0.f);
  badd.z = bi.z + (colb + 2 < 512 ? bh.z : 0.f);
  badd.w = bi.w + (colb + 3 < 512 ? bh.w : 0.f);
  float* gout = gi + (size_t)blockIdx.x * 64 * G3;
  #pragma unroll
  for (int i = 0; i < 4; ++i) {
    int bb = (ty << 2) + i;
    float4 o;
    o.x = acc[i][0] + badd.x; o.y = acc[i][1] + badd.y;
    o.z = acc[i][2] + badd.z; o.w = acc[i][3] + badd.w;
    *(float4*)(gout + (size_t)bb * G3 + colb) = o;
  }
}

// ---------------- Phase 2: single-block recurrence, fp16 dot2, 1024 thr ----------------
// grid = 64 (one block per batch). 1024 threads: j = tid>>2 in [0,256), s = tid&3,
// k-slice [64s, 64s+64). Thread rows {j, 256+j, 512+j} -> 3*64 halves = 96 half2
// regs; __launch_bounds__(1024) forces <=128 VGPRs (16 waves/CU, 4/EU -> TLP to
// overlap LDS broadcast with dot2 issue). h: fp32 carry in leaders; fp16 copy in
// LDS double buffer, slice stride 72 halves (bases at banks 0/4/8/12 -> the 4
// s-streams of each ds_read_b128 hit disjoint banks; same-s lanes broadcast).
// gi pipeline: lane s in {0,1,2} loads gate s's gi value; r/z folded pre-reduce,
// n shuffled to leader. One barrier per step. No cross-CU traffic.
__global__ __launch_bounds__(1024)
void gru_seq16(const float* __restrict__ gi, const float* __restrict__ att,
               const int* __restrict__ lengths, const float* __restrict__ Whh,
               const float* __restrict__ bhh, float* __restrict__ hws,
               float* __restrict__ out, int t0, int t1)
{
  const int b   = blockIdx.x;
  const int tid = threadIdx.x;
  const int j   = tid >> 2;
  const int s   = tid & 3;
  const int k0  = s << 6;

  __shared__ _Float16 hbuf[2][288];   // 4 slices * 72 (pad 8), double buffered

  // ---- convert W_hh rows to packed fp16 in registers (prologue only) ----
  half2v w[96];
  #pragma unroll
  for (int g = 0; g < 3; ++g) {
    const float* row = Whh + (size_t)(g * 256 + j) * H_ + k0;
    #pragma unroll
    for (int q = 0; q < 16; ++q) {
      float4 v = *(const float4*)(row + (q << 2));
      half2v a, c;
      a[0] = (_Float16)v.x; a[1] = (_Float16)v.y;
      c[0] = (_Float16)v.z; c[1] = (_Float16)v.w;
      w[g * 32 + 2 * q]     = a;
      w[g * 32 + 2 * q + 1] = c;
    }
  }

  float bhn = 0.f, h_reg = 0.f;
  if (s == 0) {
    bhn = bhh[512 + j];
    h_reg = (t0 > 0) ? hws[b * H_ + j] : 0.f;
  }
  if (tid < 256) {
    float v = (t0 > 0) ? hws[b * H_ + tid] : 0.f;
    hbuf[0][(tid >> 6) * 72 + (tid & 63)] = (_Float16)v;
  }
  int len = lengths[b]; if (len > t1) len = t1;
  __syncthreads();

  // gi/att pipeline (one step ahead): lane s loads gate s's value (s<3)
  float c_g = 0.f, c_wat = 0.f;
  if (t0 < len) {
    const float* gb = gi + (size_t)b * G3;
    if (s < 3) c_g = gb[s * 256 + j];
    if (s == 0) c_wat = att[(size_t)b * T_ + t0];
  }

  int p = 0;
  for (int t = t0; t < len; ++t) {
    float n_g = 0.f, n_wat = 0.f;
    if (t + 1 < len) {
      const float* gb = gi + ((size_t)(t + 1 - t0) * 64 + b) * G3;
      if (s < 3) n_g = gb[s * 256 + j];
      if (s == 0) n_wat = att[(size_t)b * T_ + t + 1];
    }

    float accr = 0.f, accz = 0.f, accn = 0.f;
    const _Float16* hb = &hbuf[p][s * 72];
    #pragma unroll
    for (int q = 0; q < 8; ++q) {
      half8v hv = *(const half8v*)(hb + (q << 3));
      half2v h0 = __builtin_shufflevector(hv, hv, 0, 1);
      half2v h1 = __builtin_shufflevector(hv, hv, 2, 3);
      half2v h2 = __builtin_shufflevector(hv, hv, 4, 5);
      half2v h3 = __builtin_shufflevector(hv, hv, 6, 7);
      const int qq = q << 2;
      accr = FDOT2(w[qq + 0], h0, accr);
      accr = FDOT2(w[qq + 1], h1, accr);
      accr = FDOT2(w[qq + 2], h2, accr);
      accr = FDOT2(w[qq + 3], h3, accr);
      accz = FDOT2(w[32 + qq + 0], h0, accz);
      accz = FDOT2(w[32 + qq + 1], h1, accz);
      accz = FDOT2(w[32 + qq + 2], h2, accz);
      accz = FDOT2(w[32 + qq + 3], h3, accz);
      accn = FDOT2(w[64 + qq + 0], h0, accn);
      accn = FDOT2(w[64 + qq + 1], h1, accn);
      accn = FDOT2(w[64 + qq + 2], h2, accn);
      accn = FDOT2(w[64 + qq + 3], h3, accn);
    }
    // fold gi r/z on their loader lanes before the 4-lane reduce
    if (s == 0)      accr += c_g;
    else if (s == 1) accz += c_g;
    accr += __shfl_xor(accr, 1); accr += __shfl_xor(accr, 2);
    accz += __shfl_xor(accz, 1); accz += __shfl_xor(accz, 2);
    accn += __shfl_xor(accn, 1); accn += __shfl_xor(accn, 2);
    float gn = __shfl(c_g, 2, 4);   // lane s==2's gi_n within the quad

    if (s == 0) {
      float r = 1.f / (1.f + __expf(-accr));
      float z = 1.f / (1.f + __expf(-accz));
      float e2 = __expf(2.f * (gn + r * (accn + bhn)));
      float nn = 1.f - 2.f / (e2 + 1.f);      // tanh
      float hnew = (1.f - z) * nn + z * h_reg;
      h_reg = c_wat * hnew + (1.f - c_wat) * h_reg;
      hbuf[p ^ 1][(j >> 6) * 72 + (j & 63)] = (_Float16)h_reg;
    }
    __syncthreads();
    p ^= 1;
    c_g = n_g; c_wat = n_wat;
  }

  if (s == 0) {
    hws[b * H_ + j] = h_reg;
    if (t1 == T_) out[b * H_ + j] = h_reg;
  }
}

extern "C" void kernel_launch(void* const* d_in, const int* in_sizes, int n_in,
                              void* d_out, int out_size, void* d_ws, size_t ws_size,
                              hipStream_t stream)
{
  const float* x       = (const float*)d_in[0];
  const float* att     = (const float*)d_in[1];
  const int*   lengths = (const int*)d_in[2];
  const float* Wih     = (const float*)d_in[3];
  const float* Whh     = (const float*)d_in[4];
  const float* bih     = (const float*)d_in[5];
  const float* bhh     = (const float*)d_in[6];
  float* out = (float*)d_out;

  float* hws = (float*)d_ws;                         // 64 KiB
  float* gi  = (float*)((char*)d_ws + 65536);
  const size_t used0 = 65536;
  const size_t per_t = (size_t)B_ * G3 * sizeof(float);
  size_t avail = ws_size > used0 ? ws_size - used0 : 0;
  int Tc = (int)(avail / per_t);
  if (Tc > T_) Tc = T_;
  if (Tc < 1) Tc = 1;

  for (int t0 = 0; t0 < T_; t0 += Tc) {
    int t1 = t0 + Tc; if (t1 > T_) t1 = T_;
    dim3 g1(t1 - t0, G3 / 64);
    gi_gemm<<<g1, 256, 0, stream>>>(x, Wih, bih, bhh, gi, t0);
    gru_seq16<<<B_, 1024, 0, stream>>>(gi, att, lengths, Whh, bhh, hws, out, t0, t1);
  }
}